// Round 1
// baseline (781.316 us; speedup 1.0000x reference)
//
#include <hip/hip_runtime.h>
#include <math.h>

// Problem constants
constexpr int L      = 160000;           // signal length = 4^4 * 5^4
constexpr int BATCH  = 8;                // signals per input tensor
constexpr int NBANDS = 8;
constexpr int NHOPS  = 156;              // 1024-sample hop sums needed
constexpr int NCHUNK = 155;              // windows per (signal, band)
constexpr int ND     = BATCH * NBANDS * NCHUNK; // 9920 diffs
constexpr float INV_N = 1.0f / (float)L;

__device__ __forceinline__ float2 cmulf(float2 a, float2 b) {
  return make_float2(a.x * b.x - a.y * b.y, a.x * b.y + a.y * b.x);
}

// ---------- radix butterflies (forward DFT, W_R = e^{-2pi i/R}) ----------
__device__ __forceinline__ void bf4(float2* v) {
  float2 t0 = make_float2(v[0].x + v[2].x, v[0].y + v[2].y);
  float2 t1 = make_float2(v[0].x - v[2].x, v[0].y - v[2].y);
  float2 t2 = make_float2(v[1].x + v[3].x, v[1].y + v[3].y);
  float2 t3 = make_float2(v[1].x - v[3].x, v[1].y - v[3].y);
  v[0] = make_float2(t0.x + t2.x, t0.y + t2.y);
  v[2] = make_float2(t0.x - t2.x, t0.y - t2.y);
  v[1] = make_float2(t1.x + t3.y, t1.y - t3.x);   // t1 + (-i)*t3
  v[3] = make_float2(t1.x - t3.y, t1.y + t3.x);   // t1 + ( i)*t3
}

__device__ __forceinline__ void bf5(float2* v) {
  const float c1 = 0.30901699437494745f, s1 = 0.9510565162951535f;
  const float c2 = -0.8090169943749475f, s2 = 0.5877852522924731f;
  float2 t1 = make_float2(v[1].x + v[4].x, v[1].y + v[4].y);
  float2 t3 = make_float2(v[1].x - v[4].x, v[1].y - v[4].y);
  float2 t2 = make_float2(v[2].x + v[3].x, v[2].y + v[3].y);
  float2 t4 = make_float2(v[2].x - v[3].x, v[2].y - v[3].y);
  float2 a = make_float2(v[0].x + c1 * t1.x + c2 * t2.x, v[0].y + c1 * t1.y + c2 * t2.y);
  float2 b = make_float2(s1 * t3.x + s2 * t4.x, s1 * t3.y + s2 * t4.y);
  float2 c = make_float2(v[0].x + c2 * t1.x + c1 * t2.x, v[0].y + c2 * t1.y + c1 * t2.y);
  float2 d = make_float2(s2 * t3.x - s1 * t4.x, s2 * t3.y - s1 * t4.y);
  v[0] = make_float2(v[0].x + t1.x + t2.x, v[0].y + t1.y + t2.y);
  v[1] = make_float2(a.x + b.y, a.y - b.x);  // a - i b
  v[4] = make_float2(a.x - b.y, a.y + b.x);  // a + i b
  v[2] = make_float2(c.x + d.y, c.y - d.x);  // c - i d
  v[3] = make_float2(c.x - d.y, c.y + d.x);  // c + i d
}

// ---------- kernels ----------
__global__ void pack_kernel(const float* __restrict__ in, float2* __restrict__ out) {
  int tid = blockIdx.x * 256 + threadIdx.x;
  if (tid < BATCH * L) out[tid] = make_float2(in[tid], 0.0f);
}

// Stockham DIT stage (Govindaraju formulation):
//  v[r] = in[j + r*N/R] * W_{Ns*R}^{r*(j mod Ns)};  DFT_R(v);
//  out[(j/Ns)*Ns*R + (j mod Ns) + r*Ns] = v[r];  Ns *= R per stage.
template <int R>
__global__ void fft_stage(const float2* __restrict__ in, float2* __restrict__ out, int Ns) {
  constexpr int NR = L / R;
  int tid = blockIdx.x * 256 + threadIdx.x;
  if (tid >= BATCH * NR) return;
  int s = tid / NR;
  int j = tid - s * NR;
  const float2* ib = in + (size_t)s * L;
  float2* ob = out + (size_t)s * L;
  float2 v[R];
#pragma unroll
  for (int r = 0; r < R; ++r) v[r] = ib[j + r * NR];
  int jm = j % Ns;
  float ang = -6.283185307179586f * (float)jm / (float)(Ns * R);
#pragma unroll
  for (int r = 1; r < R; ++r) {
    float sn, cs;
    sincosf((float)r * ang, &sn, &cs);
    v[r] = cmulf(v[r], make_float2(cs, sn));
  }
  if constexpr (R == 4) bf4(v); else bf5(v);
  int idxD = (j / Ns) * (Ns * R) + jm;
#pragma unroll
  for (int r = 0; r < R; ++r) ob[idxD + r * Ns] = v[r];
}

// Write conj(Y_{2jp} + i*Y_{2jp+1}) where Y_b = X .* mask_b.
// Bands disjoint: per bin at most one of the two contributes.
//   band(i): m = min(i, L-i); m==0 -> 7 else (m-1)/10000   (searchsorted-left semantics)
__global__ void mask_pair_kernel(const float2* __restrict__ X, float2* __restrict__ out, int jpair) {
  int tid = blockIdx.x * 256 + threadIdx.x;
  if (tid >= BATCH * L) return;
  int i = tid % L;
  int m = min(i, L - i);
  int b = (m == 0) ? (NBANDS - 1) : (m - 1) / 10000;
  float2 x = X[tid];
  float2 w = make_float2(0.0f, 0.0f);
  if (b == 2 * jpair)          w = make_float2(x.x, -x.y);    //  conj(X)
  else if (b == 2 * jpair + 1) w = make_float2(-x.y, -x.x);   // -i*conj(X)
  out[tid] = w;
}

// After fft(conj(Y0 + iY1)): .x = N*r0, .y = -N*r1. Square both, sum per 1024-hop.
__global__ void energy_pair_kernel(const float2* __restrict__ A, float* __restrict__ Hall,
                                   int sig0, int band0) {
  int blk = blockIdx.x;
  int s = blk / NHOPS;
  int m = blk - s * NHOPS;
  const float2* base = A + (size_t)s * L + (size_t)m * 1024;
  float ax = 0.0f, ay = 0.0f;
  for (int k = threadIdx.x; k < 1024; k += 256) {
    float2 z = base[k];
    float rx = z.x * INV_N, ry = z.y * INV_N;
    ax += rx * rx;
    ay += ry * ry;
  }
#pragma unroll
  for (int off = 32; off > 0; off >>= 1) {
    ax += __shfl_down(ax, off, 64);
    ay += __shfl_down(ay, off, 64);
  }
  __shared__ float rx4[4], ry4[4];
  int lane = threadIdx.x & 63, wv = threadIdx.x >> 6;
  if (lane == 0) { rx4[wv] = ax; ry4[wv] = ay; }
  __syncthreads();
  if (threadIdx.x == 0) {
    float tx = rx4[0] + rx4[1] + rx4[2] + rx4[3];
    float ty = ry4[0] + ry4[1] + ry4[2] + ry4[3];
    int sig = sig0 + s;
    Hall[((size_t)sig * NBANDS + band0) * NHOPS + m] = tx;
    Hall[((size_t)sig * NBANDS + band0 + 1) * NHOPS + m] = ty;
  }
}

// diff = lw - lo over [b=8][band=8][chunk=155]; out = sum(softmax(diff) * diff)
__global__ void finalize_kernel(const float* __restrict__ Hall, float* __restrict__ out) {
  __shared__ float diffs[ND];
  __shared__ float sred[256];
  int tid = threadIdx.x;
  for (int idx = tid; idx < ND; idx += 256) {
    int b = idx / (NBANDS * NCHUNK);
    int rem = idx - b * (NBANDS * NCHUNK);
    int j = rem / NCHUNK;
    int k = rem - j * NCHUNK;
    const float* hw = Hall + ((size_t)(b) * NBANDS + j) * NHOPS;
    const float* ho = Hall + ((size_t)(BATCH + b) * NBANDS + j) * NHOPS;
    float msw = (hw[k] + hw[k + 1]) * (1.0f / 2048.0f);
    float mso = (ho[k] + ho[k + 1]) * (1.0f / 2048.0f);
    float lw = -0.691f + 10.0f * log10f(msw + 1e-12f);
    float lo = -0.691f + 10.0f * log10f(mso + 1e-12f);
    diffs[idx] = lw - lo;
  }
  __syncthreads();
  float mx = -3.4e38f;
  for (int idx = tid; idx < ND; idx += 256) mx = fmaxf(mx, diffs[idx]);
  sred[tid] = mx;
  __syncthreads();
  for (int s = 128; s > 0; s >>= 1) {
    if (tid < s) sred[tid] = fmaxf(sred[tid], sred[tid + s]);
    __syncthreads();
  }
  float gmax = sred[0];
  __syncthreads();
  float se = 0.0f, swd = 0.0f;
  for (int idx = tid; idx < ND; idx += 256) {
    float d = diffs[idx];
    float e = expf(d - gmax);
    se += e;
    swd += d * e;
  }
  sred[tid] = se; __syncthreads();
  for (int s = 128; s > 0; s >>= 1) { if (tid < s) sred[tid] += sred[tid + s]; __syncthreads(); }
  float tot_se = sred[0];
  __syncthreads();
  sred[tid] = swd; __syncthreads();
  for (int s = 128; s > 0; s >>= 1) { if (tid < s) sred[tid] += sred[tid + s]; __syncthreads(); }
  if (tid == 0) out[0] = sred[0] / tot_se;
}

// ---------- host-side stage driver ----------
static void run_stages(float2* A, float2* B, float2* finalOut, hipStream_t stream) {
  const int radix[8] = {4, 4, 4, 4, 5, 5, 5, 5};
  float2* bufs[2] = {A, B};
  int cur = 0, Ns = 1;
  for (int s = 0; s < 8; ++s) {
    float2* ip = bufs[cur];
    float2* op = (s == 7) ? finalOut : bufs[cur ^ 1];
    if (radix[s] == 4)
      fft_stage<4><<<dim3((BATCH * (L / 4)) / 256), dim3(256), 0, stream>>>(ip, op, Ns);
    else
      fft_stage<5><<<dim3((BATCH * (L / 5)) / 256), dim3(256), 0, stream>>>(ip, op, Ns);
    Ns *= radix[s];
    cur ^= 1;
  }
}

extern "C" void kernel_launch(void* const* d_in, const int* in_sizes, int n_in,
                              void* d_out, int out_size, void* d_ws, size_t ws_size,
                              hipStream_t stream) {
  (void)in_sizes; (void)n_in; (void)out_size; (void)ws_size;
  char* ws = (char*)d_ws;
  const size_t BUF = (size_t)BATCH * L * sizeof(float2); // 10,240,000 B
  float2* A = (float2*)(ws);
  float2* B = (float2*)(ws + BUF);
  float2* C = (float2*)(ws + 2 * BUF);
  float* Hall = (float*)(ws + 3 * BUF);       // [16][8][156] floats

  for (int inp = 0; inp < 2; ++inp) {          // 0: watermarked, 1: original
    const float* x = (const float*)d_in[inp];
    pack_kernel<<<dim3(BATCH * L / 256), dim3(256), 0, stream>>>(x, A);
    run_stages(A, B, C, stream);               // forward FFT -> C
    for (int jp = 0; jp < 4; ++jp) {           // two bands per inverse transform
      mask_pair_kernel<<<dim3(BATCH * L / 256), dim3(256), 0, stream>>>(C, A, jp);
      run_stages(A, B, A, stream);             // fft(conj(Y)) -> A
      energy_pair_kernel<<<dim3(BATCH * NHOPS), dim3(256), 0, stream>>>(A, Hall, inp * 8, 2 * jp);
    }
  }
  finalize_kernel<<<dim3(1), dim3(256), 0, stream>>>(Hall, (float*)d_out);
}

// Round 2
// 213.414 us; speedup vs baseline: 3.6610x; 3.6610x over previous
//
#include <hip/hip_runtime.h>
#include <math.h>

// N = 160000 = 256 * 625; four-step FFT decomposition.
// Forward:  x[256*n2 + n1] --(625-FFT over n2, per n1; twiddle W_N^{n1 k2})-->
//           G'[k2][n1]     --(256-FFT over n1, per k2)--> X[k2][k1] = bin 625*k1+k2
// Inverse:  Y[k2][k1] --(256-pt sign+ FFT over k1; twiddle e^{+2pi i n1 k2/N})-->
//           H'[n1][k2] --(625-pt sign+ FFT over k2)--> N*y[256*n2 + n1]
constexpr int L      = 160000;
constexpr int BATCH  = 8;
constexpr int NB     = 8;
constexpr int NHOPS  = 156;   // 1024-sample hop sums
constexpr int NCHUNK = 155;   // 2048-windows, hop 1024
constexpr float TWO_PI = 6.28318530717958647692f;

__device__ __forceinline__ float2 cmulf(float2 a, float2 b) {
  return make_float2(a.x * b.x - a.y * b.y, a.x * b.y + a.y * b.x);
}

// ---------- signed butterflies (SIGN=-1 forward e^{-i}, +1 inverse e^{+i}) ----------
template <int SIGN>
__device__ __forceinline__ void bf4s(float2* v) {
  float2 t0 = make_float2(v[0].x + v[2].x, v[0].y + v[2].y);
  float2 t1 = make_float2(v[0].x - v[2].x, v[0].y - v[2].y);
  float2 t2 = make_float2(v[1].x + v[3].x, v[1].y + v[3].y);
  float2 t3 = make_float2(v[1].x - v[3].x, v[1].y - v[3].y);
  v[0] = make_float2(t0.x + t2.x, t0.y + t2.y);
  v[2] = make_float2(t0.x - t2.x, t0.y - t2.y);
  if constexpr (SIGN < 0) {
    v[1] = make_float2(t1.x + t3.y, t1.y - t3.x);   // t1 - i t3
    v[3] = make_float2(t1.x - t3.y, t1.y + t3.x);   // t1 + i t3
  } else {
    v[1] = make_float2(t1.x - t3.y, t1.y + t3.x);
    v[3] = make_float2(t1.x + t3.y, t1.y - t3.x);
  }
}

template <int SIGN>
__device__ __forceinline__ void bf5s(float2* v) {
  const float c1 = 0.30901699437494745f, s1 = 0.9510565162951535f;
  const float c2 = -0.8090169943749475f, s2 = 0.5877852522924731f;
  float2 t1 = make_float2(v[1].x + v[4].x, v[1].y + v[4].y);
  float2 t3 = make_float2(v[1].x - v[4].x, v[1].y - v[4].y);
  float2 t2 = make_float2(v[2].x + v[3].x, v[2].y + v[3].y);
  float2 t4 = make_float2(v[2].x - v[3].x, v[2].y - v[3].y);
  float2 a = make_float2(v[0].x + c1 * t1.x + c2 * t2.x, v[0].y + c1 * t1.y + c2 * t2.y);
  float2 b = make_float2(s1 * t3.x + s2 * t4.x, s1 * t3.y + s2 * t4.y);
  float2 c = make_float2(v[0].x + c2 * t1.x + c1 * t2.x, v[0].y + c2 * t1.y + c1 * t2.y);
  float2 d = make_float2(s2 * t3.x - s1 * t4.x, s2 * t3.y - s1 * t4.y);
  v[0] = make_float2(v[0].x + t1.x + t2.x, v[0].y + t1.y + t2.y);
  if constexpr (SIGN < 0) {
    v[1] = make_float2(a.x + b.y, a.y - b.x);  // a - i b
    v[4] = make_float2(a.x - b.y, a.y + b.x);
    v[2] = make_float2(c.x + d.y, c.y - d.x);  // c - i d
    v[3] = make_float2(c.x - d.y, c.y + d.x);
  } else {
    v[1] = make_float2(a.x - b.y, a.y + b.x);  // a + i b
    v[4] = make_float2(a.x + b.y, a.y - b.x);
    v[2] = make_float2(c.x - d.y, c.y + d.x);
    v[3] = make_float2(c.x + d.y, c.y - d.x);
  }
}

// ---------- one Stockham stage inside LDS (per-wave FFT: 64 threads, private region) ----------
template <int R, int Ns, int SIGN, int M>
__device__ __forceinline__ void lds_stage(const float2* in, float2* out, int w) {
  constexpr int NR = M / R;
  for (int j = w; j < NR; j += 64) {
    float2 v[R];
#pragma unroll
    for (int r = 0; r < R; ++r) v[r] = in[j + r * NR];
    int jm = j % Ns;
    float base = (float)SIGN * (TWO_PI / (float)(Ns * R)) * (float)jm;
#pragma unroll
    for (int r = 1; r < R; ++r) {
      float s, c;
      __sincosf((float)r * base, &s, &c);
      v[r] = cmulf(v[r], make_float2(c, s));
    }
    if constexpr (R == 4) bf4s<SIGN>(v); else bf5s<SIGN>(v);
    int od = (j / Ns) * (Ns * R) + jm;
#pragma unroll
    for (int r = 0; r < R; ++r) out[od + r * Ns] = v[r];
  }
}

template <int SIGN>
__device__ __forceinline__ void fft625(float2* a, float2* b, int w) {
  lds_stage<5, 1, SIGN, 625>(a, b, w);   __syncthreads();
  lds_stage<5, 5, SIGN, 625>(b, a, w);   __syncthreads();
  lds_stage<5, 25, SIGN, 625>(a, b, w);  __syncthreads();
  lds_stage<5, 125, SIGN, 625>(b, a, w); __syncthreads();  // result in a
}

template <int SIGN>
__device__ __forceinline__ void fft256(float2* a, float2* b, int w) {
  lds_stage<4, 1, SIGN, 256>(a, b, w);   __syncthreads();
  lds_stage<4, 4, SIGN, 256>(b, a, w);   __syncthreads();
  lds_stage<4, 16, SIGN, 256>(a, b, w);  __syncthreads();
  lds_stage<4, 64, SIGN, 256>(b, a, w);  __syncthreads();  // result in a
}

// ---------- F1: pack w+i*o, 625-FFT columns, twiddle, store transposed [k2][n1] ----------
__global__ __launch_bounds__(256) void f1_kernel(const float* __restrict__ win,
                                                 const float* __restrict__ oin,
                                                 float2* __restrict__ G) {
  __shared__ float2 A[4 * 625], B[4 * 625];
  int blk = blockIdx.x;
  int sig = blk >> 6, g = blk & 63;          // 64 groups of 4 columns
  int n1base = g * 4;
  int tid = threadIdx.x;
  const float* wp = win + (size_t)sig * L;
  const float* op = oin + (size_t)sig * L;
  for (int idx = tid; idx < 2500; idx += 256) {
    int r = idx >> 2, cc = idx & 3;
    int n = (r << 8) + n1base + cc;
    A[cc * 625 + r] = make_float2(wp[n], op[n]);
  }
  __syncthreads();
  int wv = tid >> 6, ln = tid & 63;
  fft625<-1>(A + wv * 625, B + wv * 625, ln);
  for (int idx = tid; idx < 2500; idx += 256) {
    int k2 = idx >> 2, cc = idx & 3;
    int n1 = n1base + cc;
    float ang = -(TWO_PI / (float)L) * (float)(n1 * k2);
    float s, c;
    __sincosf(ang, &s, &c);
    G[(size_t)sig * L + k2 * 256 + n1] = cmulf(A[cc * 625 + k2], make_float2(c, s));
  }
}

// ---------- F2: 256-FFT along contiguous rows -> spectrum X[k2][k1] ----------
__global__ __launch_bounds__(256) void f2_kernel(const float2* __restrict__ G,
                                                 float2* __restrict__ X) {
  __shared__ float2 A[4 * 257], B[4 * 257];   // +1 pad per row
  int blk = blockIdx.x;
  int sig = blk / 157, gr = blk % 157;
  int k2base = gr * 4;
  int tid = threadIdx.x;
  for (int idx = tid; idx < 1024; idx += 256) {
    int row = idx >> 8, k1 = idx & 255;
    int k2 = k2base + row;
    if (k2 < 625) A[row * 257 + k1] = G[(size_t)sig * L + k2 * 256 + k1];
  }
  __syncthreads();
  int wv = tid >> 6, ln = tid & 63;
  fft256<-1>(A + wv * 257, B + wv * 257, ln);
  for (int idx = tid; idx < 1024; idx += 256) {
    int row = idx >> 8, k1 = idx & 255;
    int k2 = k2base + row;
    if (k2 < 625) X[(size_t)sig * L + k2 * 256 + k1] = A[row * 257 + k1];
  }
}

// ---------- I1: mask band inline, 256-pt sign+ FFT over k1, twiddle, store [n1][k2] ----------
__global__ __launch_bounds__(256) void i1_kernel(const float2* __restrict__ X,
                                                 float2* __restrict__ H) {
  __shared__ float2 A[4 * 257], B[4 * 257];
  int blk = blockIdx.x;
  int gr = blk % 157, sb = blk / 157;
  int band = sb & 7, sig = sb >> 3;
  int k2base = gr * 4;
  int tid = threadIdx.x;
  for (int idx = tid; idx < 1024; idx += 256) {
    int row = idx >> 8, k1 = idx & 255;
    int k2 = k2base + row;
    if (k2 < 625) {
      int bin = 625 * k1 + k2;
      int m = min(bin, L - bin);
      int b = (m == 0) ? (NB - 1) : (m - 1) / 10000;
      float2 x = make_float2(0.0f, 0.0f);
      if (b == band) x = X[(size_t)sig * L + k2 * 256 + k1];
      A[row * 257 + k1] = x;
    }
  }
  __syncthreads();
  int wv = tid >> 6, ln = tid & 63;
  fft256<1>(A + wv * 257, B + wv * 257, ln);
  size_t obase = (size_t)(sig * NB + band) * L;
  for (int idx = tid; idx < 1024; idx += 256) {
    int cc = idx & 3, n1 = idx >> 2;
    int k2 = k2base + cc;
    if (k2 < 625) {
      float ang = (TWO_PI / (float)L) * (float)(n1 * k2);
      float s, c;
      __sincosf(ang, &s, &c);
      H[obase + (size_t)n1 * 625 + k2] = cmulf(A[cc * 257 + n1], make_float2(c, s));
    }
  }
}

// ---------- I2: 625-pt sign+ FFT over k2 + fused hop-energy reduction ----------
__global__ __launch_bounds__(256) void i2_kernel(const float2* __restrict__ H,
                                                 float* __restrict__ E) {
  __shared__ float2 A[4 * 625], B[4 * 625];
  __shared__ float P[2 * NHOPS];
  int blk = blockIdx.x;
  int g = blk & 63, sb = blk >> 6;
  int band = sb & 7, sig = sb >> 3;
  int n1base = g * 4;
  int tid = threadIdx.x;
  for (int idx = tid; idx < 2 * NHOPS; idx += 256) P[idx] = 0.0f;
  size_t ibase = (size_t)(sig * NB + band) * L;
#pragma unroll
  for (int row = 0; row < 4; ++row) {
    for (int k2 = tid; k2 < 625; k2 += 256) {
      A[row * 625 + k2] = H[ibase + (size_t)(n1base + row) * 625 + k2];
    }
  }
  __syncthreads();
  int wv = tid >> 6, ln = tid & 63;
  fft625<1>(A + wv * 625, B + wv * 625, ln);
  // wave wv owns n1 = n1base+wv; S[n2] = N*(rw + i*ro) at n = 256*n2 + n1.
  // hop h == n2 in [4h, 4h+4) across all n1 (1024 = 4*256).
  constexpr float invN = 1.0f / (float)L;
  const float2* S = A + wv * 625;
  for (int h = ln; h < NHOPS; h += 64) {
    float ex = 0.0f, ey = 0.0f;
#pragma unroll
    for (int d = 0; d < 4; ++d) {
      float2 z = S[4 * h + d];
      float zx = z.x * invN, zy = z.y * invN;
      ex += zx * zx;
      ey += zy * zy;
    }
    atomicAdd(&P[h], ex);
    atomicAdd(&P[NHOPS + h], ey);
  }
  __syncthreads();
  int eb = (sig * NB + band) * NHOPS;
  for (int idx = tid; idx < 2 * NHOPS; idx += 256) {
    int comp = idx / NHOPS, h = idx % NHOPS;
    atomicAdd(&E[comp * (BATCH * NB * NHOPS) + eb + h], P[idx]);
  }
}

// ---------- finalize: loudness, diff, softmax-weighted sum ----------
__global__ void finalize_kernel(const float* __restrict__ E, float* __restrict__ out) {
  constexpr int ND = BATCH * NB * NCHUNK;  // 9920
  __shared__ float diffs[ND];
  __shared__ float sred[256];
  int tid = threadIdx.x;
  for (int idx = tid; idx < ND; idx += 256) {
    int sb = idx / NCHUNK;
    int k = idx - sb * NCHUNK;
    float hw0 = E[sb * NHOPS + k], hw1 = E[sb * NHOPS + k + 1];
    float ho0 = E[64 * NHOPS + sb * NHOPS + k], ho1 = E[64 * NHOPS + sb * NHOPS + k + 1];
    float msw = (hw0 + hw1) * (1.0f / 2048.0f);
    float mso = (ho0 + ho1) * (1.0f / 2048.0f);
    float lw = -0.691f + 10.0f * log10f(msw + 1e-12f);
    float lo = -0.691f + 10.0f * log10f(mso + 1e-12f);
    diffs[idx] = lw - lo;
  }
  __syncthreads();
  float mx = -3.4e38f;
  for (int idx = tid; idx < ND; idx += 256) mx = fmaxf(mx, diffs[idx]);
  sred[tid] = mx;
  __syncthreads();
  for (int s = 128; s > 0; s >>= 1) {
    if (tid < s) sred[tid] = fmaxf(sred[tid], sred[tid + s]);
    __syncthreads();
  }
  float gmax = sred[0];
  __syncthreads();
  float se = 0.0f, swd = 0.0f;
  for (int idx = tid; idx < ND; idx += 256) {
    float d = diffs[idx];
    float e = expf(d - gmax);
    se += e;
    swd += d * e;
  }
  sred[tid] = se; __syncthreads();
  for (int s = 128; s > 0; s >>= 1) { if (tid < s) sred[tid] += sred[tid + s]; __syncthreads(); }
  float tot = sred[0];
  __syncthreads();
  sred[tid] = swd; __syncthreads();
  for (int s = 128; s > 0; s >>= 1) { if (tid < s) sred[tid] += sred[tid + s]; __syncthreads(); }
  if (tid == 0) out[0] = sred[0] / tot;
}

extern "C" void kernel_launch(void* const* d_in, const int* in_sizes, int n_in,
                              void* d_out, int out_size, void* d_ws, size_t ws_size,
                              hipStream_t stream) {
  (void)in_sizes; (void)n_in; (void)out_size; (void)ws_size;
  char* ws = (char*)d_ws;
  float2* G = (float2*)ws;                        // 10,240,000 B
  float2* X = (float2*)(ws + 10240000);           // 10,240,000 B
  float2* H = (float2*)(ws + 20480000);           // 81,920,000 B
  float*  E = (float*)(ws + 102400000);           // 79,872 B  [2][64][156]
  const float* w = (const float*)d_in[0];
  const float* o = (const float*)d_in[1];

  f1_kernel<<<dim3(BATCH * 64), dim3(256), 0, stream>>>(w, o, G);
  f2_kernel<<<dim3(BATCH * 157), dim3(256), 0, stream>>>(G, X);
  i1_kernel<<<dim3(BATCH * NB * 157), dim3(256), 0, stream>>>(X, H);
  hipMemsetAsync(E, 0, 2 * BATCH * NB * NHOPS * sizeof(float), stream);
  i2_kernel<<<dim3(BATCH * NB * 64), dim3(256), 0, stream>>>(H, E);
  finalize_kernel<<<dim3(1), dim3(256), 0, stream>>>(E, (float*)d_out);
}